// Round 1
// baseline (300.599 us; speedup 1.0000x reference)
//
#include <hip/hip_runtime.h>
#include <stdint.h>

// SingleHeadAttention: B=4, S=4096, D_MODEL=1024, HEAD=64
// Plan: bf16 MFMA 16x16x32 for projection + flash attention.
//   k1 prep_wt:  Wq/Wk/Wv fp32 [1024][64] -> Wt bf16 [192][1024] (transposed)
//   k2 proj_rope: Q=rope(xWq)*0.125, K=rope(xWk), V -> Vt[b][d][s], all bf16 in ws
//   k3 attn: flash attention, 64-key tiles in LDS (stride 72 to avoid bank conflicts)

static constexpr int S_LEN  = 4096;
static constexpr int DMODEL = 1024;

typedef __attribute__((ext_vector_type(8))) short bf16x8;
typedef __attribute__((ext_vector_type(4))) float f32x4;

#define MFMA16(a, b, c) __builtin_amdgcn_mfma_f32_16x16x32_bf16((a), (b), (c), 0, 0, 0)

__device__ __forceinline__ unsigned short f2b(float f) {
    union { float f; unsigned int u; } v;
    v.f = f;
    unsigned int u = v.u;
    u += 0x7fffu + ((u >> 16) & 1u);   // round-to-nearest-even
    return (unsigned short)(u >> 16);
}

// ---------------- k1: W transpose + bf16 convert -> Wt[192][1024] ----------------
__global__ __launch_bounds__(256) void prep_wt(const float* __restrict__ Wq,
                                               const float* __restrict__ Wk,
                                               const float* __restrict__ Wv,
                                               unsigned short* __restrict__ Wt) {
    int idx = blockIdx.x * 256 + threadIdx.x;   // grid = 768 -> 196608 exact
    int c = idx >> 10;                          // output col 0..191
    int k = idx & 1023;
    int mat = c >> 6, n = c & 63;
    const float* W = (mat == 0) ? Wq : (mat == 1) ? Wk : Wv;
    Wt[idx] = f2b(W[k * 64 + n]);
}

// ---------------- k2: QKV projection + RoPE ----------------
// grid 256 blocks, block 256 = 4 waves; wave w: rows [blk*64 + w*16, +16), cols 0..191
__global__ __launch_bounds__(256) void proj_rope(const float* __restrict__ x,
                                                 const unsigned short* __restrict__ Wt,
                                                 unsigned short* __restrict__ Qg,
                                                 unsigned short* __restrict__ Kg,
                                                 unsigned short* __restrict__ Vtg) {
    const int tid  = threadIdx.x;
    const int wave = tid >> 6, lane = tid & 63;
    const int l15  = lane & 15, quad = lane >> 4;
    const int mbase = blockIdx.x * 64;
    const int arow  = mbase + wave * 16 + l15;   // A-operand row (m = lane&15)

    f32x4 acc[12];
#pragma unroll
    for (int nt = 0; nt < 12; ++nt) acc[nt] = (f32x4){0.f, 0.f, 0.f, 0.f};

    const float* xrow = x + (size_t)arow * DMODEL;

    for (int kc = 0; kc < 32; ++kc) {
        const int k0 = kc * 32 + quad * 8;       // A[k] = quad*8 + j within 32-chunk
        const float4* xp = reinterpret_cast<const float4*>(xrow + k0);
        float4 a0 = xp[0], a1 = xp[1];
        bf16x8 af;
        af[0] = (short)f2b(a0.x); af[1] = (short)f2b(a0.y);
        af[2] = (short)f2b(a0.z); af[3] = (short)f2b(a0.w);
        af[4] = (short)f2b(a1.x); af[5] = (short)f2b(a1.y);
        af[6] = (short)f2b(a1.z); af[7] = (short)f2b(a1.w);
#pragma unroll
        for (int nt = 0; nt < 12; ++nt) {
            // B[k][n]: n = nt*16 + l15, k = k0..k0+7 -> 16B contiguous from Wt row n
            bf16x8 bf = *reinterpret_cast<const bf16x8*>(Wt + (nt * 16 + l15) * 1024 + k0);
            acc[nt] = MFMA16(af, bf, acc[nt]);
        }
    }

    // Epilogue: C/D layout row = quad*4+r, col = nt*16 + l15.
    // RoPE pairs cols (2i, 2i+1) -> adjacent lanes -> shfl_xor(.,1).
#pragma unroll
    for (int nt = 0; nt < 12; ++nt) {
        const int mat = nt >> 2;                 // 0=Q 1=K 2=V
        const int d   = (nt & 3) * 16 + l15;     // head dim 0..63
        float theta = 0.f;
        if (mat < 2) {
            int i = d >> 1;
            theta = 1.0f / __powf(10000.0f, (float)i * (1.0f / 32.0f));
        }
#pragma unroll
        for (int r = 0; r < 4; ++r) {
            const int gr   = mbase + wave * 16 + quad * 4 + r;   // global row
            const int b    = gr >> 12;
            const int spos = gr & (S_LEN - 1);
            float v = acc[nt][r];
            if (mat < 2) {
                float partner = __shfl_xor(v, 1);
                float fr = (float)spos * theta;
                float sn, cs;
                sincosf(fr, &sn, &cs);
                float outv = (d & 1) ? (v * cs + partner * sn)   // odd index: b*cos + a*sin
                                     : (v * cs - partner * sn);  // even index: a*cos - b*sin
                if (mat == 0) outv *= 0.125f;                    // fold score scale into Q
                unsigned short bv = f2b(outv);
                if (mat == 0) Qg[(size_t)gr * 64 + d] = bv;
                else          Kg[(size_t)gr * 64 + d] = bv;
            } else {
                Vtg[(size_t)b * (64 * S_LEN) + (size_t)d * S_LEN + spos] = f2b(v);
            }
        }
    }
}

// ---------------- k3: causal flash attention ----------------
// grid (64 q-tiles, 4 batches), block 256 = 4 waves; wave w handles q rows [qt*64+w*16, +16)
__global__ __launch_bounds__(256) void attn(const unsigned short* __restrict__ Qg,
                                            const unsigned short* __restrict__ Kg,
                                            const unsigned short* __restrict__ Vtg,
                                            float* __restrict__ out) {
    __shared__ __align__(16) unsigned short Klds[64 * 72];      // [key][dim], stride 72
    __shared__ __align__(16) unsigned short Vlds[64 * 72];      // [dim][key], stride 72
    __shared__ __align__(16) unsigned short Plds[4 * 16 * 72];  // per-wave P, [row][key]

    const int tid  = threadIdx.x;
    const int wave = tid >> 6, lane = tid & 63;
    const int l15  = lane & 15, quad = lane >> 4;
    const int qt = blockIdx.x, b = blockIdx.y;
    const int qbase = qt * 64;

    // Q A-frags (held for whole kernel): row m = l15, k = kc*32 + quad*8 + j
    bf16x8 qa[2];
    {
        const unsigned short* qrow = Qg + (size_t)(b * S_LEN + qbase + wave * 16 + l15) * 64;
        qa[0] = *reinterpret_cast<const bf16x8*>(qrow + quad * 8);
        qa[1] = *reinterpret_cast<const bf16x8*>(qrow + 32 + quad * 8);
    }

    f32x4 o[4];
    float m[4], l[4];
#pragma unroll
    for (int nt = 0; nt < 4; ++nt) o[nt] = (f32x4){0.f, 0.f, 0.f, 0.f};
#pragma unroll
    for (int r = 0; r < 4; ++r) { m[r] = -1e30f; l[r] = 0.f; }

    for (int kt = 0; kt <= qt; ++kt) {
        // ---- stage K tile [64 keys][64 dims] and Vt tile [64 dims][64 keys] ----
#pragma unroll
        for (int it = 0; it < 2; ++it) {
            int idx = it * 256 + tid;            // 0..511
            int r0 = idx >> 3, g = idx & 7;      // row, 16B-granule
            *reinterpret_cast<uint4*>(Klds + r0 * 72 + g * 8) =
                *reinterpret_cast<const uint4*>(Kg + (size_t)(b * S_LEN + kt * 64 + r0) * 64 + g * 8);
            *reinterpret_cast<uint4*>(Vlds + r0 * 72 + g * 8) =
                *reinterpret_cast<const uint4*>(Vtg + (size_t)b * (64 * S_LEN) + (size_t)r0 * S_LEN + kt * 64 + g * 8);
        }
        __syncthreads();

        // ---- S = Q K^T (scale pre-folded into Q) ----
        f32x4 s[4];
#pragma unroll
        for (int nt = 0; nt < 4; ++nt) {
            bf16x8 kb0 = *reinterpret_cast<const bf16x8*>(Klds + (nt * 16 + l15) * 72 + quad * 8);
            bf16x8 kb1 = *reinterpret_cast<const bf16x8*>(Klds + (nt * 16 + l15) * 72 + 32 + quad * 8);
            f32x4 z = (f32x4){0.f, 0.f, 0.f, 0.f};
            z = MFMA16(qa[0], kb0, z);
            z = MFMA16(qa[1], kb1, z);
            s[nt] = z;
        }

        // ---- causal mask (only diagonal tile needs it) ----
        if (kt == qt) {
#pragma unroll
            for (int nt = 0; nt < 4; ++nt) {
                int key_l = nt * 16 + l15;
#pragma unroll
                for (int r = 0; r < 4; ++r) {
                    int q_l = wave * 16 + quad * 4 + r;
                    if (key_l > q_l) s[nt][r] = -1e30f;
                }
            }
        }

        // ---- online softmax (row = quad*4+r, 16 keys per nt across l15 lanes) ----
#pragma unroll
        for (int r = 0; r < 4; ++r) {
            float tm = fmaxf(fmaxf(s[0][r], s[1][r]), fmaxf(s[2][r], s[3][r]));
            tm = fmaxf(tm, __shfl_xor(tm, 1));
            tm = fmaxf(tm, __shfl_xor(tm, 2));
            tm = fmaxf(tm, __shfl_xor(tm, 4));
            tm = fmaxf(tm, __shfl_xor(tm, 8));
            float mn = fmaxf(m[r], tm);
            float alpha = __expf(m[r] - mn);
            float ps = 0.f;
#pragma unroll
            for (int nt = 0; nt < 4; ++nt) {
                float p = __expf(s[nt][r] - mn);
                s[nt][r] = p;
                ps += p;
            }
            ps += __shfl_xor(ps, 1);
            ps += __shfl_xor(ps, 2);
            ps += __shfl_xor(ps, 4);
            ps += __shfl_xor(ps, 8);
            l[r] = l[r] * alpha + ps;
            m[r] = mn;
#pragma unroll
            for (int nt = 0; nt < 4; ++nt) o[nt][r] *= alpha;
        }

        // ---- P: C-layout -> LDS -> A-layout (bf16) ----
#pragma unroll
        for (int nt = 0; nt < 4; ++nt)
#pragma unroll
            for (int r = 0; r < 4; ++r)
                Plds[wave * 1152 + (quad * 4 + r) * 72 + nt * 16 + l15] = f2b(s[nt][r]);
        __syncthreads();

        // ---- O += P V : A = P[m=l15][k=keys], B = V[k=key][n=dim] from Vt rows ----
#pragma unroll
        for (int nt = 0; nt < 4; ++nt) {
#pragma unroll
            for (int kc = 0; kc < 2; ++kc) {
                bf16x8 pa = *reinterpret_cast<const bf16x8*>(Plds + wave * 1152 + l15 * 72 + kc * 32 + quad * 8);
                bf16x8 vb = *reinterpret_cast<const bf16x8*>(Vlds + (nt * 16 + l15) * 72 + kc * 32 + quad * 8);
                o[nt] = MFMA16(pa, vb, o[nt]);
            }
        }
        __syncthreads();   // protect K/V tiles before next staging
    }

    // ---- epilogue: out[b][q][d] = o / l, fp32 ----
#pragma unroll
    for (int nt = 0; nt < 4; ++nt)
#pragma unroll
        for (int r = 0; r < 4; ++r) {
            int grow = b * S_LEN + qbase + wave * 16 + quad * 4 + r;
            out[(size_t)grow * 64 + nt * 16 + l15] = o[nt][r] / l[r];
        }
}

extern "C" void kernel_launch(void* const* d_in, const int* in_sizes, int n_in,
                              void* d_out, int out_size, void* d_ws, size_t ws_size,
                              hipStream_t stream) {
    const float* x  = (const float*)d_in[0];
    const float* Wq = (const float*)d_in[1];
    const float* Wk = (const float*)d_in[2];
    const float* Wv = (const float*)d_in[3];
    float* out = (float*)d_out;

    unsigned short* Qg  = (unsigned short*)d_ws;   // [16384][64] bf16 (pre-scaled 1/8, roped)
    unsigned short* Kg  = Qg + (1u << 20);         // [16384][64] bf16 (roped)
    unsigned short* Vtg = Kg + (1u << 20);         // [4][64][4096] bf16 (transposed V)
    unsigned short* Wt  = Vtg + (1u << 20);        // [192][1024] bf16

    prep_wt<<<768, 256, 0, stream>>>(Wq, Wk, Wv, Wt);
    proj_rope<<<256, 256, 0, stream>>>(x, Wt, Qg, Kg, Vtg);
    attn<<<dim3(64, 4), 256, 0, stream>>>(Qg, Kg, Vtg, out);
}

// Round 2
// 251.253 us; speedup vs baseline: 1.1964x; 1.1964x over previous
//
#include <hip/hip_runtime.h>
#include <stdint.h>

// SingleHeadAttention: B=4, S=4096, D_MODEL=1024, HEAD=64
//   k1 prep_wt:   Wq/Wk/Wv fp32 [1024][64] -> Wt bf16 [192][1024] (transposed)
//   k2 proj_rope: Q=rope(xWq)*0.125, K=rope(xWk), V -> Vt[b][d][s], bf16 in ws
//                 grid 1024 x 16-row blocks (4 waves split the 192 cols) for occupancy
//   k3 attn_split: causal flash attention, split-K over NS=4 key ranges -> partials
//   k4 combine:   merge NS partials (log-sum-exp style) -> fp32 out

static constexpr int S_LEN  = 4096;
static constexpr int DMODEL = 1024;
static constexpr int NS     = 4;      // key-dimension splits for attention

typedef __attribute__((ext_vector_type(8))) short bf16x8;
typedef __attribute__((ext_vector_type(4))) float f32x4;

#define MFMA16(a, b, c) __builtin_amdgcn_mfma_f32_16x16x32_bf16((a), (b), (c), 0, 0, 0)

__device__ __forceinline__ unsigned short f2b(float f) {
    union { float f; unsigned int u; } v;
    v.f = f;
    unsigned int u = v.u;
    u += 0x7fffu + ((u >> 16) & 1u);   // round-to-nearest-even
    return (unsigned short)(u >> 16);
}
__device__ __forceinline__ float b2f(unsigned short b) {
    union { unsigned int u; float f; } v;
    v.u = ((unsigned int)b) << 16;
    return v.f;
}

// ---------------- k1: W transpose + bf16 convert -> Wt[192][1024] ----------------
__global__ __launch_bounds__(256) void prep_wt(const float* __restrict__ Wq,
                                               const float* __restrict__ Wk,
                                               const float* __restrict__ Wv,
                                               unsigned short* __restrict__ Wt) {
    int idx = blockIdx.x * 256 + threadIdx.x;   // grid = 768 -> 196608 exact
    int c = idx >> 10;                          // output col 0..191
    int k = idx & 1023;
    int mat = c >> 6, n = c & 63;
    const float* W = (mat == 0) ? Wq : (mat == 1) ? Wk : Wv;
    Wt[idx] = f2b(W[k * 64 + n]);
}

// ---------------- k2: QKV projection + RoPE ----------------
// grid 1024 blocks, block 256 = 4 waves; block = rows [blk*16, +16), wave w = cols [w*48, +48)
__global__ __launch_bounds__(256) void proj_rope(const float* __restrict__ x,
                                                 const unsigned short* __restrict__ Wt,
                                                 unsigned short* __restrict__ Qg,
                                                 unsigned short* __restrict__ Kg,
                                                 unsigned short* __restrict__ Vtg) {
    const int tid  = threadIdx.x;
    const int wave = tid >> 6, lane = tid & 63;
    const int l15  = lane & 15, quad = lane >> 4;
    const int rbase = blockIdx.x * 16;
    const int arow  = rbase + l15;               // A-operand row (m = lane&15)

    f32x4 acc[3];
#pragma unroll
    for (int ft = 0; ft < 3; ++ft) acc[ft] = (f32x4){0.f, 0.f, 0.f, 0.f};

    const float* xrow = x + (size_t)arow * DMODEL;

    for (int kc = 0; kc < 32; ++kc) {
        const int k0 = kc * 32 + quad * 8;       // A[k] = quad*8 + j within 32-chunk
        const float4* xp = reinterpret_cast<const float4*>(xrow + k0);
        float4 a0 = xp[0], a1 = xp[1];
        bf16x8 af;
        af[0] = (short)f2b(a0.x); af[1] = (short)f2b(a0.y);
        af[2] = (short)f2b(a0.z); af[3] = (short)f2b(a0.w);
        af[4] = (short)f2b(a1.x); af[5] = (short)f2b(a1.y);
        af[6] = (short)f2b(a1.z); af[7] = (short)f2b(a1.w);
#pragma unroll
        for (int ft = 0; ft < 3; ++ft) {
            // B[k][n]: n = wave*48 + ft*16 + l15, k = k0..k0+7 contiguous from Wt row n
            bf16x8 bf = *reinterpret_cast<const bf16x8*>(Wt + (wave * 48 + ft * 16 + l15) * 1024 + k0);
            acc[ft] = MFMA16(af, bf, acc[ft]);
        }
    }

    // Epilogue: C/D layout row = quad*4+r, col = wave*48 + ft*16 + l15.
#pragma unroll
    for (int ft = 0; ft < 3; ++ft) {
        const int col0 = wave * 48 + ft * 16;
        const int mat  = col0 >> 6;              // 0=Q 1=K 2=V
        const int d    = (col0 & 63) + l15;      // head dim 0..63
        float theta = 0.f;
        if (mat < 2) {
            int i = d >> 1;
            theta = 1.0f / __powf(10000.0f, (float)i * (1.0f / 32.0f));
        }
#pragma unroll
        for (int r = 0; r < 4; ++r) {
            const int gr   = rbase + quad * 4 + r;   // global row
            const int b    = gr >> 12;
            const int spos = gr & (S_LEN - 1);
            float v = acc[ft][r];
            if (mat < 2) {
                float partner = __shfl_xor(v, 1);    // RoPE pair lives in adjacent lane
                float fr = (float)spos * theta;
                float sn, cs;
                sincosf(fr, &sn, &cs);
                float outv = (d & 1) ? (v * cs + partner * sn)
                                     : (v * cs - partner * sn);
                if (mat == 0) outv *= 0.125f;        // fold score scale into Q
                unsigned short bv = f2b(outv);
                if (mat == 0) Qg[(size_t)gr * 64 + d] = bv;
                else          Kg[(size_t)gr * 64 + d] = bv;
            } else {
                Vtg[(size_t)b * (64 * S_LEN) + (size_t)d * S_LEN + spos] = f2b(v);
            }
        }
    }
}

// ---------------- k3: causal flash attention, split-K ----------------
// grid (64 qt, NS splits, 4 b), block 256 = 4 waves; wave w: q rows [qt*64+w*16, +16)
__global__ __launch_bounds__(256) void attn_split(const unsigned short* __restrict__ Qg,
                                                  const unsigned short* __restrict__ Kg,
                                                  const unsigned short* __restrict__ Vtg,
                                                  unsigned short* __restrict__ OP,
                                                  float* __restrict__ ML) {
    __shared__ __align__(16) unsigned short Klds[64 * 72];      // [key][dim], stride 72
    __shared__ __align__(16) unsigned short Vlds[64 * 72];      // [dim][key], stride 72
    __shared__ __align__(16) unsigned short Plds[4 * 16 * 72];  // per-wave P, [row][key]

    const int tid  = threadIdx.x;
    const int wave = tid >> 6, lane = tid & 63;
    const int l15  = lane & 15, quad = lane >> 4;
    const int qt = blockIdx.x, split = blockIdx.y, b = blockIdx.z;
    const int qbase = qt * 64;

    const int total = qt + 1;                    // causal: tiles 0..qt
    const int chunk = (total + NS - 1) / NS;
    const int k0 = split * chunk;
    const int k1 = (k0 + chunk < total) ? (k0 + chunk) : total;

    // Q A-frags: row m = l15, k = kc*32 + quad*8 + j
    bf16x8 qa[2];
    {
        const unsigned short* qrow = Qg + (size_t)(b * S_LEN + qbase + wave * 16 + l15) * 64;
        qa[0] = *reinterpret_cast<const bf16x8*>(qrow + quad * 8);
        qa[1] = *reinterpret_cast<const bf16x8*>(qrow + 32 + quad * 8);
    }

    f32x4 o[4];
    float m[4], l[4];
#pragma unroll
    for (int nt = 0; nt < 4; ++nt) o[nt] = (f32x4){0.f, 0.f, 0.f, 0.f};
#pragma unroll
    for (int r = 0; r < 4; ++r) { m[r] = -1e30f; l[r] = 0.f; }

    // staging geometry: idx = it*256+tid over 512 granules; r0=idx>>3 row, g=idx&7
    const size_t kgbase  = (size_t)(b * S_LEN) * 64;
    const size_t vtbase  = (size_t)b * (64 * S_LEN);

    uint4 kreg[2], vreg[2];
    if (k0 < k1) {
#pragma unroll
        for (int it = 0; it < 2; ++it) {
            int idx = it * 256 + tid, r0 = idx >> 3, g = idx & 7;
            kreg[it] = *reinterpret_cast<const uint4*>(Kg  + kgbase + (size_t)(k0 * 64 + r0) * 64 + g * 8);
            vreg[it] = *reinterpret_cast<const uint4*>(Vtg + vtbase + (size_t)r0 * S_LEN + k0 * 64 + g * 8);
        }
    }

    for (int kt = k0; kt < k1; ++kt) {
        __syncthreads();                         // previous iter done reading K/V LDS
#pragma unroll
        for (int it = 0; it < 2; ++it) {
            int idx = it * 256 + tid, r0 = idx >> 3, g = idx & 7;
            *reinterpret_cast<uint4*>(Klds + r0 * 72 + g * 8) = kreg[it];
            *reinterpret_cast<uint4*>(Vlds + r0 * 72 + g * 8) = vreg[it];
        }
        __syncthreads();                         // LDS tiles ready

        if (kt + 1 < k1) {                       // prefetch next tile (overlaps compute)
#pragma unroll
            for (int it = 0; it < 2; ++it) {
                int idx = it * 256 + tid, r0 = idx >> 3, g = idx & 7;
                kreg[it] = *reinterpret_cast<const uint4*>(Kg  + kgbase + (size_t)((kt + 1) * 64 + r0) * 64 + g * 8);
                vreg[it] = *reinterpret_cast<const uint4*>(Vtg + vtbase + (size_t)r0 * S_LEN + (kt + 1) * 64 + g * 8);
            }
        }

        // ---- S = Q K^T (scale pre-folded into Q) ----
        f32x4 s[4];
#pragma unroll
        for (int nt = 0; nt < 4; ++nt) {
            bf16x8 kb0 = *reinterpret_cast<const bf16x8*>(Klds + (nt * 16 + l15) * 72 + quad * 8);
            bf16x8 kb1 = *reinterpret_cast<const bf16x8*>(Klds + (nt * 16 + l15) * 72 + 32 + quad * 8);
            f32x4 z = (f32x4){0.f, 0.f, 0.f, 0.f};
            z = MFMA16(qa[0], kb0, z);
            z = MFMA16(qa[1], kb1, z);
            s[nt] = z;
        }

        // ---- causal mask (diagonal tile only) ----
        if (kt == qt) {
#pragma unroll
            for (int nt = 0; nt < 4; ++nt) {
                int key_l = nt * 16 + l15;
#pragma unroll
                for (int r = 0; r < 4; ++r) {
                    int q_l = wave * 16 + quad * 4 + r;
                    if (key_l > q_l) s[nt][r] = -1e30f;
                }
            }
        }

        // ---- online softmax (row = quad*4+r; 16 keys per nt across l15 lanes) ----
#pragma unroll
        for (int r = 0; r < 4; ++r) {
            float tm = fmaxf(fmaxf(s[0][r], s[1][r]), fmaxf(s[2][r], s[3][r]));
            tm = fmaxf(tm, __shfl_xor(tm, 1));
            tm = fmaxf(tm, __shfl_xor(tm, 2));
            tm = fmaxf(tm, __shfl_xor(tm, 4));
            tm = fmaxf(tm, __shfl_xor(tm, 8));
            float mn = fmaxf(m[r], tm);
            float alpha = __expf(m[r] - mn);
            float ps = 0.f;
#pragma unroll
            for (int nt = 0; nt < 4; ++nt) {
                float p = __expf(s[nt][r] - mn);
                s[nt][r] = p;
                ps += p;
            }
            ps += __shfl_xor(ps, 1);
            ps += __shfl_xor(ps, 2);
            ps += __shfl_xor(ps, 4);
            ps += __shfl_xor(ps, 8);
            l[r] = l[r] * alpha + ps;
            m[r] = mn;
#pragma unroll
            for (int nt = 0; nt < 4; ++nt) o[nt][r] *= alpha;
        }

        // ---- P: C-layout -> per-wave LDS -> A-layout. No barrier needed:
        // Plds region is private to this wave; compiler-inserted lgkmcnt orders it.
#pragma unroll
        for (int nt = 0; nt < 4; ++nt)
#pragma unroll
            for (int r = 0; r < 4; ++r)
                Plds[wave * 1152 + (quad * 4 + r) * 72 + nt * 16 + l15] = f2b(s[nt][r]);

        // ---- O += P V ----
#pragma unroll
        for (int nt = 0; nt < 4; ++nt) {
#pragma unroll
            for (int kc = 0; kc < 2; ++kc) {
                bf16x8 pa = *reinterpret_cast<const bf16x8*>(Plds + wave * 1152 + l15 * 72 + kc * 32 + quad * 8);
                bf16x8 vb = *reinterpret_cast<const bf16x8*>(Vlds + (nt * 16 + l15) * 72 + kc * 32 + quad * 8);
                o[nt] = MFMA16(pa, vb, o[nt]);
            }
        }
    }

    // ---- epilogue: write unnormalized partial O (bf16) + per-row m,l ----
    const size_t prow_base = ((size_t)(split * 4 + b)) * S_LEN;
#pragma unroll
    for (int nt = 0; nt < 4; ++nt)
#pragma unroll
        for (int r = 0; r < 4; ++r) {
            int row = qbase + wave * 16 + quad * 4 + r;
            OP[(prow_base + row) * 64 + nt * 16 + l15] = f2b(o[nt][r]);
        }
    if (l15 == 0) {
#pragma unroll
        for (int r = 0; r < 4; ++r) {
            int row = qbase + wave * 16 + quad * 4 + r;
            ML[(prow_base + row) * 2 + 0] = m[r];
            ML[(prow_base + row) * 2 + 1] = l[r];
        }
    }
}

// ---------------- k4: combine NS partials ----------------
__global__ __launch_bounds__(256) void combine(const unsigned short* __restrict__ OP,
                                               const float* __restrict__ ML,
                                               float* __restrict__ out) {
    int idx = blockIdx.x * 256 + threadIdx.x;    // over 4*4096*64 = 1,048,576
    int d   = idx & 63;
    int row = (idx >> 6) & (S_LEN - 1);
    int b   = idx >> 18;

    float mv[NS], lv[NS];
    float M = -1e30f;
#pragma unroll
    for (int s = 0; s < NS; ++s) {
        size_t base = ((size_t)(s * 4 + b) * S_LEN + row) * 2;
        mv[s] = ML[base];
        lv[s] = ML[base + 1];
        M = fmaxf(M, mv[s]);
    }
    float num = 0.f, den = 0.f;
#pragma unroll
    for (int s = 0; s < NS; ++s) {
        float sc = __expf(mv[s] - M);
        den += sc * lv[s];
        num += sc * b2f(OP[((size_t)(s * 4 + b) * S_LEN + row) * 64 + d]);
    }
    out[idx] = num / den;
}

extern "C" void kernel_launch(void* const* d_in, const int* in_sizes, int n_in,
                              void* d_out, int out_size, void* d_ws, size_t ws_size,
                              hipStream_t stream) {
    const float* x  = (const float*)d_in[0];
    const float* Wq = (const float*)d_in[1];
    const float* Wk = (const float*)d_in[2];
    const float* Wv = (const float*)d_in[3];
    float* out = (float*)d_out;

    unsigned char* base = (unsigned char*)d_ws;
    unsigned short* Qg  = (unsigned short*)(base);                       // 2 MB
    unsigned short* Kg  = (unsigned short*)(base + (2u << 20));          // 2 MB
    unsigned short* Vtg = (unsigned short*)(base + (4u << 20));          // 2 MB
    unsigned short* Wt  = (unsigned short*)(base + (6u << 20));          // 384 KB
    float*          ML  = (float*)(base + (6u << 20) + (1u << 19));      // 512 KB
    unsigned short* OP  = (unsigned short*)(base + (7u << 20));          // 8 MB -> 15 MB total

    prep_wt<<<768, 256, 0, stream>>>(Wq, Wk, Wv, Wt);
    proj_rope<<<1024, 256, 0, stream>>>(x, Wt, Qg, Kg, Vtg);
    attn_split<<<dim3(64, NS, 4), 256, 0, stream>>>(Qg, Kg, Vtg, OP, ML);
    combine<<<4096, 256, 0, stream>>>(OP, ML, out);
}